// Round 3
// baseline (265.169 us; speedup 1.0000x reference)
//
#include <hip/hip_runtime.h>
#include <math.h>

#define NEDGE 4000
#define NPE   25
#define DIN   128
#define NPROJ 128
#define NANCH 64
#define NROWS (NEDGE*NPE)   // 100000

// Reference x-array value at global sorted-row g, replicated bit-exactly:
// x = ((R - Pofs - 1)/(D-1)) * 0.99999f + 1e-5f + seg   (all fp32, no FMA fusion)
__device__ __forceinline__ float xval_of(int g) {
  int ee = g / NPE;
  int jj = g - ee * NPE;
  float t1 = __fdiv_rn((float)jj, 24.0f);
  float t2 = __fmul_rn(t1, 0.99999f);
  float t3 = __fadd_rn(t2, 1e-5f);
  return __fadd_rn(t3, (float)ee);
}

// --- K1: Wt[k][p] = theta[p][k] / ||theta[p]|| (transposed for GEMM LDS reads)
__global__ __launch_bounds__(128) void k_prep(const float* __restrict__ theta,
                                              float* __restrict__ Wt) {
  int p = threadIdx.x;
  float s = 0.f;
  #pragma unroll 8
  for (int k = 0; k < DIN; ++k) { float t = theta[p*DIN + k]; s = fmaf(t, t, s); }
  float nrm = sqrtf(s);
  for (int k = 0; k < DIN; ++k)
    Wt[k*NPROJ + p] = __fdiv_rn(theta[p*DIN + k], nrm);
}

// --- K2: Xslices = X @ W^T.  Block tile 32 rows x 128 cols, thread tile 4x4.
// sW staged in two 64-k halves (48KB LDS total -> 3 blocks/CU).
__global__ __launch_bounds__(256) void k_gemm(const float* __restrict__ X,
                                              const float* __restrict__ Wt,
                                              float* __restrict__ Xs) {
  __shared__ float sW[64 * NPROJ];   // 32KB, [k][p]
  __shared__ float sX[32 * DIN];     // 16KB, [r][k]
  const int tid = threadIdx.x;
  const int rbase = blockIdx.x * 32;
  {
    const float4* src = (const float4*)(X + (size_t)rbase * DIN);
    float4* dst = (float4*)sX;
    #pragma unroll
    for (int i = 0; i < 4; ++i) dst[tid + 256*i] = src[tid + 256*i];
  }
  const int cg = tid & 31, rg = tid >> 5;
  const int p0 = cg * 4, r0 = rg * 4;
  float acc[4][4] = {};
  for (int ph = 0; ph < 2; ++ph) {
    __syncthreads();   // sX ready (ph0) / sW reads of previous phase done (ph1)
    {
      const float4* src = (const float4*)(Wt + ph * 64 * NPROJ);
      float4* dst = (float4*)sW;
      #pragma unroll
      for (int i = 0; i < 8; ++i) dst[tid + 256*i] = src[tid + 256*i];
    }
    __syncthreads();
    #pragma unroll
    for (int k0 = 0; k0 < 64; k0 += 4) {
      float4 w[4];
      #pragma unroll
      for (int i = 0; i < 4; ++i) w[i] = *(const float4*)&sW[(k0+i)*NPROJ + p0];
      #pragma unroll
      for (int i = 0; i < 4; ++i) {
        float4 xv = *(const float4*)&sX[(r0+i)*DIN + ph*64 + k0];
        const float xs[4] = {xv.x, xv.y, xv.z, xv.w};
        #pragma unroll
        for (int kk = 0; kk < 4; ++kk) {
          acc[i][0] = fmaf(xs[kk], w[kk].x, acc[i][0]);
          acc[i][1] = fmaf(xs[kk], w[kk].y, acc[i][1]);
          acc[i][2] = fmaf(xs[kk], w[kk].z, acc[i][2]);
          acc[i][3] = fmaf(xs[kk], w[kk].w, acc[i][3]);
        }
      }
    }
  }
  #pragma unroll
  for (int i = 0; i < 4; ++i) {
    float4 st = make_float4(acc[i][0], acc[i][1], acc[i][2], acc[i][3]);
    *(float4*)&Xs[(size_t)(rbase + r0 + i)*NPROJ + p0] = st;
  }
}

// --- K3a: per-column partial min/max over row stripes (coalesced)
__global__ __launch_bounds__(256) void k_mma(const float* __restrict__ Xs,
                                             float* __restrict__ pmin,
                                             float* __restrict__ pmax) {
  int tid = threadIdx.x;
  int p = tid & 127, rr = tid >> 7;
  int slot = blockIdx.x * 2 + rr;          // 0..511
  float mn = INFINITY, mx = -INFINITY;
  for (int r = slot; r < NROWS; r += 512) {
    float v = Xs[(size_t)r*NPROJ + p];
    mn = fminf(mn, v); mx = fmaxf(mx, v);
  }
  pmin[slot*NPROJ + p] = mn;
  pmax[slot*NPROJ + p] = mx;
}

// --- K3b: finish min/max reduction (min/max are order-independent -> exact)
__global__ __launch_bounds__(1024) void k_mmb(const float* __restrict__ pmin,
                                              const float* __restrict__ pmax,
                                              float* __restrict__ fmn,
                                              float* __restrict__ fmx) {
  __shared__ float smn[8*NPROJ], smx[8*NPROJ];
  int tid = threadIdx.x;
  int p = tid & 127, g = tid >> 7;         // g 0..7
  float mn = INFINITY, mx = -INFINITY;
  #pragma unroll 8
  for (int i = 0; i < 64; ++i) {
    int slot = g*64 + i;
    mn = fminf(mn, pmin[slot*NPROJ + p]);
    mx = fmaxf(mx, pmax[slot*NPROJ + p]);
  }
  smn[g*NPROJ + p] = mn; smx[g*NPROJ + p] = mx;
  __syncthreads();
  if (g == 0) {
    #pragma unroll
    for (int i = 1; i < 8; ++i) {
      mn = fminf(mn, smn[i*NPROJ + p]);
      mx = fmaxf(mx, smx[i*NPROJ + p]);
    }
    fmn[p] = mn; fmx[p] = mx;
  }
}

// --- K4: per edge: stable rank-sort of 25 values per column + prev-edge top-2,
//         searchsorted replication, lerp, weighted mean over anchors.
__global__ __launch_bounds__(128) void k_main(const float* __restrict__ Xs,
                                              const float* __restrict__ fmnA,
                                              const float* __restrict__ fmxA,
                                              const float* __restrict__ anchors,
                                              const float* __restrict__ weight,
                                              float* __restrict__ out) {
  __shared__ float svals[NPE * NPROJ];   // sorted values of edge e, [rank][p]
  __shared__ float sprev[2 * NPROJ];     // ranks 23,24 of edge e-1
  __shared__ int   sind[NANCH];
  __shared__ float stt[NANCH];
  const int e = blockIdx.x;
  const int p = threadIdx.x;
  const float ef = (float)e;
  const float fmin = fmnA[p];
  const float denom = __fadd_rn(__fsub_rn(fmxA[p], fmin), 1e-12f);

  // stable sort via rank computation: lexicographic (key, original index)
  float v[NPE], key[NPE];
  #pragma unroll
  for (int j = 0; j < NPE; ++j) {
    float x = Xs[(size_t)(e*NPE + j)*NPROJ + p];
    v[j] = x;
    key[j] = __fadd_rn(__fdiv_rn(__fsub_rn(x, fmin), denom), ef);
  }
  #pragma unroll
  for (int i = 0; i < NPE; ++i) {
    int cnt = 0;
    #pragma unroll
    for (int j = 0; j < NPE; ++j)
      cnt += ((key[j] < key[i]) || (key[j] == key[i] && j < i)) ? 1 : 0;
    svals[cnt*NPROJ + p] = v[i];
  }
  if (e > 0) {
    // stable top-2 of previous edge by (key, idx): ties keep LATER index on top
    const float efp = (float)(e - 1);
    float k1 = -INFINITY, k2 = -INFINITY, v1 = 0.f, v2 = 0.f;
    #pragma unroll
    for (int j = 0; j < NPE; ++j) {
      float x = Xs[(size_t)((e-1)*NPE + j)*NPROJ + p];
      float kk = __fadd_rn(__fdiv_rn(__fsub_rn(x, fmin), denom), efp);
      if (kk >= k1)      { k2 = k1; v2 = v1; k1 = kk; v1 = x; }
      else if (kk >= k2) { k2 = kk; v2 = x; }
    }
    sprev[p]         = v2;   // rank 23 of edge e-1
    sprev[NPROJ + p] = v1;   // rank 24 of edge e-1
  }
  __syncthreads();

  // searchsorted(x, xnew, side='left'), candidates in [25e-1, 25e+24]
  if (p < NANCH) {
    const int m = p;
    // JAX linspace(0,1,64)[m] = fl(m * fl(1/63))  (no numpy endpoint fixup)
    const float delta = __fdiv_rn(1.0f, 63.0f);
    float g = __fmul_rn((float)m, delta);
    g = __fadd_rn(__fmul_rn(g, 0.99998f), 1e-5f);
    const float xnew = __fadd_rn(ef, g);
    int lo = e*NPE - 1; if (lo < 0) lo = 0;
    const int hi = e*NPE + (NPE - 1);
    int ind = -1;
    for (int j = lo; j <= hi; ++j) {
      float xg = xval_of(j);
      if (ind < 0 && xg >= xnew) ind = j;
    }
    if (ind < 0) ind = hi;
    if (ind < 1) ind = 1;                          // clip(ind, 1, N-1)
    float x0 = xval_of(ind - 1);
    float x1 = xval_of(ind);
    stt[m]  = __fdiv_rn(__fsub_rn(xnew, x0), __fsub_rn(x1, x0));
    sind[m] = ind;
  }
  __syncthreads();

  float acc = 0.f;
  const int base = e * NPE;
  for (int m = 0; m < NANCH; ++m) {
    const int ind = sind[m];
    const float t = stt[m];
    const int o1 = ind - base;       // -1..24
    const int o0 = o1 - 1;           // -2..23
    const float y1 = (o1 >= 0) ? svals[o1*NPROJ + p] : sprev[(o1 + 2)*NPROJ + p];
    const float y0 = (o0 >= 0) ? svals[o0*NPROJ + p] : sprev[(o0 + 2)*NPROJ + p];
    const float ynew = __fadd_rn(y0, __fmul_rn(__fsub_rn(y1, y0), t));
    const float emb  = __fsub_rn(anchors[m*NPROJ + p], ynew);
    acc = __fadd_rn(acc, __fmul_rn(weight[p*NANCH + m], emb));
  }
  out[(size_t)e*NPROJ + p] = __fmul_rn(acc, 0.015625f);   // mean over 64 (exact pow2)
  // second output (edges): harness reads whole d_out as float32 -> store as float
  if (p == 0) out[NEDGE*NPROJ + e] = (float)e;
}

extern "C" void kernel_launch(void* const* d_in, const int* in_sizes, int n_in,
                              void* d_out, int out_size, void* d_ws, size_t ws_size,
                              hipStream_t stream) {
  (void)in_sizes; (void)n_in; (void)out_size; (void)ws_size;
  const float* X      = (const float*)d_in[0];
  const float* theta  = (const float*)d_in[1];
  const float* anchor = (const float*)d_in[2];
  const float* weight = (const float*)d_in[3];
  float* out = (float*)d_out;
  float* ws  = (float*)d_ws;

  float* Xs   = ws;                          // 100000*128
  float* Wt   = Xs   + (size_t)NROWS*NPROJ;  // 128*128
  float* pmin = Wt   + DIN*NPROJ;            // 512*128
  float* pmax = pmin + 512*NPROJ;            // 512*128
  float* fmn  = pmax + 512*NPROJ;            // 128
  float* fmx  = fmn  + NPROJ;                // 128

  k_prep<<<1, 128, 0, stream>>>(theta, Wt);
  k_gemm<<<NROWS/32, 256, 0, stream>>>(X, Wt, Xs);
  k_mma <<<256, 256, 0, stream>>>(Xs, pmin, pmax);
  k_mmb <<<1, 1024, 0, stream>>>(pmin, pmax, fmn, fmx);
  k_main<<<NEDGE, 128, 0, stream>>>(Xs, fmn, fmx, anchor, weight, out);
}

// Round 4
// 228.780 us; speedup vs baseline: 1.1591x; 1.1591x over previous
//
#include <hip/hip_runtime.h>
#include <math.h>

#define NEDGE 4000
#define NPE   25
#define DIN   128
#define NPROJ 128
#define NANCH 64
#define NROWS (NEDGE*NPE)   // 100000
#define NBLK  (NROWS/32)    // 3125 gemm blocks

// Reference x-array value at global sorted-row g, replicated bit-exactly:
// x = ((R - Pofs - 1)/(D-1)) * 0.99999f + 1e-5f + seg   (all fp32, no FMA fusion)
__device__ __forceinline__ float xval_of(int g) {
  int ee = g / NPE;
  int jj = g - ee * NPE;
  float t1 = __fdiv_rn((float)jj, 24.0f);
  float t2 = __fmul_rn(t1, 0.99999f);
  float t3 = __fadd_rn(t2, 1e-5f);
  return __fadd_rn(t3, (float)ee);
}

// --- K1: Wt[k][p] = theta[p][k] / ||theta[p]|| (transposed for GEMM LDS reads)
// Arithmetic identical to the round-3 passing version (sequential fmaf).
__global__ __launch_bounds__(128) void k_prep(const float* __restrict__ theta,
                                              float* __restrict__ Wt) {
  int p = threadIdx.x;
  float s = 0.f;
  #pragma unroll 8
  for (int k = 0; k < DIN; ++k) { float t = theta[p*DIN + k]; s = fmaf(t, t, s); }
  float nrm = sqrtf(s);
  for (int k = 0; k < DIN; ++k)
    Wt[k*NPROJ + p] = __fdiv_rn(theta[p*DIN + k], nrm);
}

// --- K2: Xslices = X @ W^T.  32 rows x 128 cols per block, thread tile 4x4.
// sW staged in FOUR 32-k phases (32KB LDS total -> 5 blocks/CU).
// Epilogue: per-block per-column min/max from acc registers (exact; fuses k_mma).
__global__ __launch_bounds__(256) void k_gemm(const float* __restrict__ X,
                                              const float* __restrict__ Wt,
                                              float* __restrict__ Xs,
                                              float* __restrict__ pmin,
                                              float* __restrict__ pmax) {
  __shared__ float sW[32 * NPROJ];   // 16KB, [k][p]
  __shared__ float sX[32 * DIN];     // 16KB, [r][k]
  const int tid = threadIdx.x;
  const int rbase = blockIdx.x * 32;
  {
    const float4* src = (const float4*)(X + (size_t)rbase * DIN);
    float4* dst = (float4*)sX;
    #pragma unroll
    for (int i = 0; i < 4; ++i) dst[tid + 256*i] = src[tid + 256*i];
  }
  const int cg = tid & 31, rg = tid >> 5;
  const int p0 = cg * 4, r0 = rg * 4;
  float acc[4][4] = {};
  for (int ph = 0; ph < 4; ++ph) {
    __syncthreads();   // sX ready / previous phase's sW reads done
    {
      const float4* src = (const float4*)(Wt + ph * 32 * NPROJ);
      float4* dst = (float4*)sW;
      #pragma unroll
      for (int i = 0; i < 4; ++i) dst[tid + 256*i] = src[tid + 256*i];
    }
    __syncthreads();
    #pragma unroll
    for (int k0 = 0; k0 < 32; k0 += 4) {
      float4 w[4];
      #pragma unroll
      for (int i = 0; i < 4; ++i) w[i] = *(const float4*)&sW[(k0+i)*NPROJ + p0];
      #pragma unroll
      for (int i = 0; i < 4; ++i) {
        float4 xv = *(const float4*)&sX[(r0+i)*DIN + ph*32 + k0];
        const float xs[4] = {xv.x, xv.y, xv.z, xv.w};
        #pragma unroll
        for (int kk = 0; kk < 4; ++kk) {
          acc[i][0] = fmaf(xs[kk], w[kk].x, acc[i][0]);
          acc[i][1] = fmaf(xs[kk], w[kk].y, acc[i][1]);
          acc[i][2] = fmaf(xs[kk], w[kk].z, acc[i][2]);
          acc[i][3] = fmaf(xs[kk], w[kk].w, acc[i][3]);
        }
      }
    }
  }
  #pragma unroll
  for (int i = 0; i < 4; ++i) {
    float4 st = make_float4(acc[i][0], acc[i][1], acc[i][2], acc[i][3]);
    *(float4*)&Xs[(size_t)(rbase + r0 + i)*NPROJ + p0] = st;
  }
  // --- fused min/max over this block's 32 rows, per column (reuse sX as scratch)
  __syncthreads();                       // all sX/sW reads done
  float* rmn = sX;                       // [8][128]
  float* rmx = sX + 8*NPROJ;             // [8][128]
  #pragma unroll
  for (int c = 0; c < 4; ++c) {
    float mn = fminf(fminf(acc[0][c], acc[1][c]), fminf(acc[2][c], acc[3][c]));
    float mx = fmaxf(fmaxf(acc[0][c], acc[1][c]), fmaxf(acc[2][c], acc[3][c]));
    rmn[rg*NPROJ + p0 + c] = mn;
    rmx[rg*NPROJ + p0 + c] = mx;
  }
  __syncthreads();
  if (tid < NPROJ) {
    float mn = rmn[tid], mx = rmx[tid];
    #pragma unroll
    for (int g2 = 1; g2 < 8; ++g2) {
      mn = fminf(mn, rmn[g2*NPROJ + tid]);
      mx = fmaxf(mx, rmx[g2*NPROJ + tid]);
    }
    pmin[(size_t)blockIdx.x*NPROJ + tid] = mn;
    pmax[(size_t)blockIdx.x*NPROJ + tid] = mx;
  }
}

// --- K3a: reduce 3125 block-partials -> 25 partials (25 blocks x 125 slots)
__global__ __launch_bounds__(256) void k_red1(const float* __restrict__ pmin,
                                              const float* __restrict__ pmax,
                                              float* __restrict__ imn,
                                              float* __restrict__ imx) {
  __shared__ float smn[NPROJ], smx[NPROJ];
  const int tid = threadIdx.x, p = tid & 127, h = tid >> 7;
  const int b = blockIdx.x;
  float mn = INFINITY, mx = -INFINITY;
  for (int s = 125*b + h; s < 125*(b+1); s += 2) {
    mn = fminf(mn, pmin[(size_t)s*NPROJ + p]);
    mx = fmaxf(mx, pmax[(size_t)s*NPROJ + p]);
  }
  if (h == 1) { smn[p] = mn; smx[p] = mx; }
  __syncthreads();
  if (h == 0) {
    imn[b*NPROJ + p] = fminf(mn, smn[p]);
    imx[b*NPROJ + p] = fmaxf(mx, smx[p]);
  }
}

// --- K3b: reduce 25 partials -> final per-column min/max
__global__ __launch_bounds__(256) void k_red2(const float* __restrict__ imn,
                                              const float* __restrict__ imx,
                                              float* __restrict__ fmn,
                                              float* __restrict__ fmx) {
  __shared__ float smn[NPROJ], smx[NPROJ];
  const int tid = threadIdx.x, p = tid & 127, h = tid >> 7;
  float mn = INFINITY, mx = -INFINITY;
  for (int s = h; s < 25; s += 2) {
    mn = fminf(mn, imn[s*NPROJ + p]);
    mx = fmaxf(mx, imx[s*NPROJ + p]);
  }
  if (h == 1) { smn[p] = mn; smx[p] = mx; }
  __syncthreads();
  if (h == 0) { fmn[p] = fminf(mn, smn[p]); fmx[p] = fmaxf(mx, smx[p]); }
}

// --- K4: per edge: stable rank-sort (integer keys) + prev-edge top-2,
//         searchsorted replication, lerp, weighted mean over anchors.
// Keys are non-negative floats -> IEEE order == unsigned bit-pattern order.
// Tie-break j<i is compile-time in the unrolled loop: one u32 compare per pair.
__global__ __launch_bounds__(128) void k_main(const float* __restrict__ Xs,
                                              const float* __restrict__ fmnA,
                                              const float* __restrict__ fmxA,
                                              const float* __restrict__ anchors,
                                              const float* __restrict__ weight,
                                              float* __restrict__ out) {
  __shared__ float svals[NPE * NPROJ];   // sorted values of edge e, [rank][p]
  __shared__ float sprev[2 * NPROJ];     // ranks 23,24 of edge e-1
  __shared__ int   sind[NANCH];
  __shared__ float stt[NANCH];
  const int e = blockIdx.x;
  const int p = threadIdx.x;
  const float ef = (float)e;
  const float fmin = fmnA[p];
  const float denom = __fadd_rn(__fsub_rn(fmxA[p], fmin), 1e-12f);

  float v[NPE];
  unsigned ku[NPE];
  #pragma unroll
  for (int j = 0; j < NPE; ++j) {
    float x = Xs[(size_t)(e*NPE + j)*NPROJ + p];
    v[j] = x;
    ku[j] = __float_as_uint(__fadd_rn(__fdiv_rn(__fsub_rn(x, fmin), denom), ef));
  }
  #pragma unroll
  for (int i = 0; i < NPE; ++i) {
    int cnt = 0;
    #pragma unroll
    for (int j = 0; j < NPE; ++j) {
      if (j == i) continue;
      cnt += (j < i) ? (ku[j] <= ku[i]) : (ku[j] < ku[i]);
    }
    svals[cnt*NPROJ + p] = v[i];
  }
  if (e > 0) {
    // stable top-2 of previous edge by (key, idx): ties keep LATER index on top
    const float efp = (float)(e - 1);
    unsigned k1 = 0u, k2 = 0u;            // all keys >= +0.0 -> bits >= 0
    float v1 = 0.f, v2 = 0.f;
    #pragma unroll
    for (int j = 0; j < NPE; ++j) {
      float x = Xs[(size_t)((e-1)*NPE + j)*NPROJ + p];
      unsigned kk = __float_as_uint(
          __fadd_rn(__fdiv_rn(__fsub_rn(x, fmin), denom), efp));
      if (kk >= k1)      { k2 = k1; v2 = v1; k1 = kk; v1 = x; }
      else if (kk >= k2) { k2 = kk; v2 = x; }
    }
    sprev[p]         = v2;   // rank 23 of edge e-1
    sprev[NPROJ + p] = v1;   // rank 24 of edge e-1
  }
  __syncthreads();

  // searchsorted(x, xnew, side='left'), candidates in [25e-1, 25e+24]
  if (p < NANCH) {
    const int m = p;
    // JAX linspace(0,1,64)[m] = fl(m * fl(1/63))  (no numpy endpoint fixup)
    const float delta = __fdiv_rn(1.0f, 63.0f);
    float g = __fmul_rn((float)m, delta);
    g = __fadd_rn(__fmul_rn(g, 0.99998f), 1e-5f);
    const float xnew = __fadd_rn(ef, g);
    int lo = e*NPE - 1; if (lo < 0) lo = 0;
    const int hi = e*NPE + (NPE - 1);
    int ind = -1;
    for (int j = lo; j <= hi; ++j) {
      float xg = xval_of(j);
      if (ind < 0 && xg >= xnew) ind = j;
    }
    if (ind < 0) ind = hi;
    if (ind < 1) ind = 1;                          // clip(ind, 1, N-1)
    float x0 = xval_of(ind - 1);
    float x1 = xval_of(ind);
    stt[m]  = __fdiv_rn(__fsub_rn(xnew, x0), __fsub_rn(x1, x0));
    sind[m] = ind;
  }
  __syncthreads();

  float acc = 0.f;
  const int base = e * NPE;
  for (int m = 0; m < NANCH; ++m) {
    const int ind = sind[m];
    const float t = stt[m];
    const int o1 = ind - base;       // -1..24
    const int o0 = o1 - 1;           // -2..23
    const float y1 = (o1 >= 0) ? svals[o1*NPROJ + p] : sprev[(o1 + 2)*NPROJ + p];
    const float y0 = (o0 >= 0) ? svals[o0*NPROJ + p] : sprev[(o0 + 2)*NPROJ + p];
    const float ynew = __fadd_rn(y0, __fmul_rn(__fsub_rn(y1, y0), t));
    const float emb  = __fsub_rn(anchors[m*NPROJ + p], ynew);
    acc = __fadd_rn(acc, __fmul_rn(weight[p*NANCH + m], emb));
  }
  out[(size_t)e*NPROJ + p] = __fmul_rn(acc, 0.015625f);   // mean over 64 (exact pow2)
  // second output (edges): harness reads whole d_out as float32 -> store as float
  if (p == 0) out[NEDGE*NPROJ + e] = (float)e;
}

extern "C" void kernel_launch(void* const* d_in, const int* in_sizes, int n_in,
                              void* d_out, int out_size, void* d_ws, size_t ws_size,
                              hipStream_t stream) {
  (void)in_sizes; (void)n_in; (void)out_size; (void)ws_size;
  const float* X      = (const float*)d_in[0];
  const float* theta  = (const float*)d_in[1];
  const float* anchor = (const float*)d_in[2];
  const float* weight = (const float*)d_in[3];
  float* out = (float*)d_out;
  float* ws  = (float*)d_ws;

  float* Xs   = ws;                          // 100000*128
  float* Wt   = Xs   + (size_t)NROWS*NPROJ;  // 128*128
  float* pmin = Wt   + DIN*NPROJ;            // 3125*128
  float* pmax = pmin + (size_t)NBLK*NPROJ;   // 3125*128
  float* imn  = pmax + (size_t)NBLK*NPROJ;   // 25*128
  float* imx  = imn  + 25*NPROJ;             // 25*128
  float* fmn  = imx  + 25*NPROJ;             // 128
  float* fmx  = fmn  + NPROJ;                // 128

  k_prep<<<1, 128, 0, stream>>>(theta, Wt);
  k_gemm<<<NBLK, 256, 0, stream>>>(X, Wt, Xs, pmin, pmax);
  k_red1<<<25, 256, 0, stream>>>(pmin, pmax, imn, imx);
  k_red2<<<1, 256, 0, stream>>>(imn, imx, fmn, fmx);
  k_main<<<NEDGE, 128, 0, stream>>>(Xs, fmn, fmx, anchor, weight, out);
}

// Round 5
// 221.410 us; speedup vs baseline: 1.1976x; 1.0333x over previous
//
#include <hip/hip_runtime.h>
#include <math.h>

#define NEDGE 4000
#define NPE   25
#define DIN   128
#define NPROJ 128
#define NANCH 64
#define NROWS (NEDGE*NPE)   // 100000
#define NBLK  (NROWS/32)    // 3125 gemm blocks

// Reference x-array value at global sorted-row g, replicated bit-exactly:
// x = ((R - Pofs - 1)/(D-1)) * 0.99999f + 1e-5f + seg   (all fp32, no FMA fusion)
__device__ __forceinline__ float xval_of(int g) {
  int ee = g / NPE;
  int jj = g - ee * NPE;
  float t1 = __fdiv_rn((float)jj, 24.0f);
  float t2 = __fmul_rn(t1, 0.99999f);
  float t3 = __fadd_rn(t2, 1e-5f);
  return __fadd_rn(t3, (float)ee);
}

// --- K1: Wt[k][p] = theta[p][k]/||theta[p]|| (transposed for GEMM LDS reads)
//         wT[m][p] = weight[p][m]            (transposed for coalesced k_main reads)
__global__ __launch_bounds__(128) void k_prep(const float* __restrict__ theta,
                                              const float* __restrict__ weight,
                                              float* __restrict__ Wt,
                                              float* __restrict__ wT) {
  int p = threadIdx.x;
  float s = 0.f;
  #pragma unroll 8
  for (int k = 0; k < DIN; ++k) { float t = theta[p*DIN + k]; s = fmaf(t, t, s); }
  float nrm = sqrtf(s);
  for (int k = 0; k < DIN; ++k)
    Wt[k*NPROJ + p] = __fdiv_rn(theta[p*DIN + k], nrm);
  #pragma unroll
  for (int m = 0; m < NANCH; ++m)
    wT[m*NPROJ + p] = weight[p*NANCH + m];
}

// --- K2: Xslices = X @ W^T.  32 rows x 128 cols per block, thread tile 4x4.
// sW staged in FOUR 32-k phases (32KB LDS total).
// Epilogue: per-block per-column min/max from acc registers (exact).
__global__ __launch_bounds__(256) void k_gemm(const float* __restrict__ X,
                                              const float* __restrict__ Wt,
                                              float* __restrict__ Xs,
                                              float* __restrict__ pmin,
                                              float* __restrict__ pmax) {
  __shared__ float sW[32 * NPROJ];   // 16KB, [k][p]
  __shared__ float sX[32 * DIN];     // 16KB, [r][k]
  const int tid = threadIdx.x;
  const int rbase = blockIdx.x * 32;
  {
    const float4* src = (const float4*)(X + (size_t)rbase * DIN);
    float4* dst = (float4*)sX;
    #pragma unroll
    for (int i = 0; i < 4; ++i) dst[tid + 256*i] = src[tid + 256*i];
  }
  const int cg = tid & 31, rg = tid >> 5;
  const int p0 = cg * 4, r0 = rg * 4;
  float acc[4][4] = {};
  for (int ph = 0; ph < 4; ++ph) {
    __syncthreads();   // sX ready / previous phase's sW reads done
    {
      const float4* src = (const float4*)(Wt + ph * 32 * NPROJ);
      float4* dst = (float4*)sW;
      #pragma unroll
      for (int i = 0; i < 4; ++i) dst[tid + 256*i] = src[tid + 256*i];
    }
    __syncthreads();
    #pragma unroll
    for (int k0 = 0; k0 < 32; k0 += 4) {
      float4 w[4];
      #pragma unroll
      for (int i = 0; i < 4; ++i) w[i] = *(const float4*)&sW[(k0+i)*NPROJ + p0];
      #pragma unroll
      for (int i = 0; i < 4; ++i) {
        float4 xv = *(const float4*)&sX[(r0+i)*DIN + ph*32 + k0];
        const float xs[4] = {xv.x, xv.y, xv.z, xv.w};
        #pragma unroll
        for (int kk = 0; kk < 4; ++kk) {
          acc[i][0] = fmaf(xs[kk], w[kk].x, acc[i][0]);
          acc[i][1] = fmaf(xs[kk], w[kk].y, acc[i][1]);
          acc[i][2] = fmaf(xs[kk], w[kk].z, acc[i][2]);
          acc[i][3] = fmaf(xs[kk], w[kk].w, acc[i][3]);
        }
      }
    }
  }
  #pragma unroll
  for (int i = 0; i < 4; ++i) {
    float4 st = make_float4(acc[i][0], acc[i][1], acc[i][2], acc[i][3]);
    *(float4*)&Xs[(size_t)(rbase + r0 + i)*NPROJ + p0] = st;
  }
  // --- fused min/max over this block's 32 rows, per column (reuse sX as scratch)
  __syncthreads();                       // all sX/sW reads done
  float* rmn = sX;                       // [8][128]
  float* rmx = sX + 8*NPROJ;             // [8][128]
  #pragma unroll
  for (int c = 0; c < 4; ++c) {
    float mn = fminf(fminf(acc[0][c], acc[1][c]), fminf(acc[2][c], acc[3][c]));
    float mx = fmaxf(fmaxf(acc[0][c], acc[1][c]), fmaxf(acc[2][c], acc[3][c]));
    rmn[rg*NPROJ + p0 + c] = mn;
    rmx[rg*NPROJ + p0 + c] = mx;
  }
  __syncthreads();
  if (tid < NPROJ) {
    float mn = rmn[tid], mx = rmx[tid];
    #pragma unroll
    for (int g2 = 1; g2 < 8; ++g2) {
      mn = fminf(mn, rmn[g2*NPROJ + tid]);
      mx = fmaxf(mx, rmx[g2*NPROJ + tid]);
    }
    pmin[(size_t)blockIdx.x*NPROJ + tid] = mn;
    pmax[(size_t)blockIdx.x*NPROJ + tid] = mx;
  }
}

// --- K3a: reduce 3125 block-partials -> 25 partials (25 blocks x 125 slots)
__global__ __launch_bounds__(256) void k_red1(const float* __restrict__ pmin,
                                              const float* __restrict__ pmax,
                                              float* __restrict__ imn,
                                              float* __restrict__ imx) {
  __shared__ float smn[NPROJ], smx[NPROJ];
  const int tid = threadIdx.x, p = tid & 127, h = tid >> 7;
  const int b = blockIdx.x;
  float mn = INFINITY, mx = -INFINITY;
  for (int s = 125*b + h; s < 125*(b+1); s += 2) {
    mn = fminf(mn, pmin[(size_t)s*NPROJ + p]);
    mx = fmaxf(mx, pmax[(size_t)s*NPROJ + p]);
  }
  if (h == 1) { smn[p] = mn; smx[p] = mx; }
  __syncthreads();
  if (h == 0) {
    imn[b*NPROJ + p] = fminf(mn, smn[p]);
    imx[b*NPROJ + p] = fmaxf(mx, smx[p]);
  }
}

// --- K3b: reduce 25 partials -> final per-column min/max
__global__ __launch_bounds__(256) void k_red2(const float* __restrict__ imn,
                                              const float* __restrict__ imx,
                                              float* __restrict__ fmn,
                                              float* __restrict__ fmx) {
  __shared__ float smn[NPROJ], smx[NPROJ];
  const int tid = threadIdx.x, p = tid & 127, h = tid >> 7;
  float mn = INFINITY, mx = -INFINITY;
  for (int s = h; s < 25; s += 2) {
    mn = fminf(mn, imn[s*NPROJ + p]);
    mx = fmaxf(mx, imx[s*NPROJ + p]);
  }
  if (h == 1) { smn[p] = mn; smx[p] = mx; }
  __syncthreads();
  if (h == 0) { fmn[p] = fminf(mn, smn[p]); fmx[p] = fmaxf(mx, smx[p]); }
}

// --- K4: per edge: stable rank-sort (u32 keys) + prev-edge top-2,
//         searchsorted via LDS grid table, lerp, weighted mean over anchors.
__global__ __launch_bounds__(128) void k_main(const float* __restrict__ Xs,
                                              const float* __restrict__ fmnA,
                                              const float* __restrict__ fmxA,
                                              const float* __restrict__ anchors,
                                              const float* __restrict__ wT,
                                              float* __restrict__ out) {
  __shared__ float svals[NPE * NPROJ];   // sorted values of edge e, [rank][p]
  __shared__ float sprev[2 * NPROJ];     // ranks 23,24 of edge e-1
  __shared__ float sxv[26];              // x-grid values for candidate range
  __shared__ int   sind[NANCH];
  __shared__ float stt[NANCH];
  const int e = blockIdx.x;
  const int p = threadIdx.x;
  const float ef = (float)e;
  const float fmin = fmnA[p];
  const float denom = __fadd_rn(__fsub_rn(fmxA[p], fmin), 1e-12f);

  const int base_j = (e == 0) ? 0 : (e*NPE - 1);
  const int n_j    = (e == 0) ? NPE : (NPE + 1);
  if (p < n_j) sxv[p] = xval_of(base_j + p);

  float v[NPE];
  unsigned ku[NPE];
  #pragma unroll
  for (int j = 0; j < NPE; ++j) {
    float x = Xs[(size_t)(e*NPE + j)*NPROJ + p];
    v[j] = x;
    ku[j] = __float_as_uint(__fadd_rn(__fdiv_rn(__fsub_rn(x, fmin), denom), ef));
  }
  #pragma unroll
  for (int i = 0; i < NPE; ++i) {
    int cnt = 0;
    #pragma unroll
    for (int j = 0; j < NPE; ++j) {
      if (j == i) continue;
      cnt += (j < i) ? (ku[j] <= ku[i]) : (ku[j] < ku[i]);
    }
    svals[cnt*NPROJ + p] = v[i];
  }
  if (e > 0) {
    // stable top-2 of previous edge by (key, idx): ties keep LATER index on top
    const float efp = (float)(e - 1);
    unsigned k1 = 0u, k2 = 0u;            // all keys >= +0.0 -> bits >= 0
    float v1 = 0.f, v2 = 0.f;
    #pragma unroll
    for (int j = 0; j < NPE; ++j) {
      float x = Xs[(size_t)((e-1)*NPE + j)*NPROJ + p];
      unsigned kk = __float_as_uint(
          __fadd_rn(__fdiv_rn(__fsub_rn(x, fmin), denom), efp));
      if (kk >= k1)      { k2 = k1; v2 = v1; k1 = kk; v1 = x; }
      else if (kk >= k2) { k2 = kk; v2 = x; }
    }
    sprev[p]         = v2;   // rank 23 of edge e-1
    sprev[NPROJ + p] = v1;   // rank 24 of edge e-1
  }
  __syncthreads();

  // searchsorted(x, xnew, side='left') over candidates [base_j, base_j+n_j)
  if (p < NANCH) {
    const int m = p;
    // JAX linspace(0,1,64)[m] = fl(m * fl(1/63))  (no numpy endpoint fixup)
    const float delta = __fdiv_rn(1.0f, 63.0f);
    float g = __fmul_rn((float)m, delta);
    g = __fadd_rn(__fmul_rn(g, 0.99998f), 1e-5f);
    const float xnew = __fadd_rn(ef, g);
    int ind = -1;
    for (int t = 0; t < n_j; ++t) {
      if (ind < 0 && sxv[t] >= xnew) ind = base_j + t;
    }
    if (ind < 0) ind = base_j + n_j - 1;
    if (ind < 1) ind = 1;                          // clip(ind, 1, N-1)
    float x0 = xval_of(ind - 1);
    float x1 = xval_of(ind);
    stt[m]  = __fdiv_rn(__fsub_rn(xnew, x0), __fsub_rn(x1, x0));
    sind[m] = ind;
  }
  __syncthreads();

  float acc = 0.f;
  const int base = e * NPE;
  for (int m = 0; m < NANCH; ++m) {
    const int ind = sind[m];
    const float t = stt[m];
    const int o1 = ind - base;       // -1..24
    const int o0 = o1 - 1;           // -2..23
    const float y1 = (o1 >= 0) ? svals[o1*NPROJ + p] : sprev[(o1 + 2)*NPROJ + p];
    const float y0 = (o0 >= 0) ? svals[o0*NPROJ + p] : sprev[(o0 + 2)*NPROJ + p];
    const float ynew = __fadd_rn(y0, __fmul_rn(__fsub_rn(y1, y0), t));
    const float emb  = __fsub_rn(anchors[m*NPROJ + p], ynew);
    acc = __fadd_rn(acc, __fmul_rn(wT[m*NPROJ + p], emb));
  }
  out[(size_t)e*NPROJ + p] = __fmul_rn(acc, 0.015625f);   // mean over 64 (exact pow2)
  // second output (edges): harness reads whole d_out as float32 -> store as float
  if (p == 0) out[NEDGE*NPROJ + e] = (float)e;
}

extern "C" void kernel_launch(void* const* d_in, const int* in_sizes, int n_in,
                              void* d_out, int out_size, void* d_ws, size_t ws_size,
                              hipStream_t stream) {
  (void)in_sizes; (void)n_in; (void)out_size; (void)ws_size;
  const float* X      = (const float*)d_in[0];
  const float* theta  = (const float*)d_in[1];
  const float* anchor = (const float*)d_in[2];
  const float* weight = (const float*)d_in[3];
  float* out = (float*)d_out;
  float* ws  = (float*)d_ws;

  float* Xs   = ws;                          // 100000*128
  float* Wt   = Xs   + (size_t)NROWS*NPROJ;  // 128*128
  float* wT   = Wt   + DIN*NPROJ;            // 64*128
  float* pmin = wT   + NANCH*NPROJ;          // 3125*128
  float* pmax = pmin + (size_t)NBLK*NPROJ;   // 3125*128
  float* imn  = pmax + (size_t)NBLK*NPROJ;   // 25*128
  float* imx  = imn  + 25*NPROJ;             // 25*128
  float* fmn  = imx  + 25*NPROJ;             // 128
  float* fmx  = fmn  + NPROJ;                // 128

  k_prep<<<1, 128, 0, stream>>>(theta, weight, Wt, wT);
  k_gemm<<<NBLK, 256, 0, stream>>>(X, Wt, Xs, pmin, pmax);
  k_red1<<<25, 256, 0, stream>>>(pmin, pmax, imn, imx);
  k_red2<<<1, 256, 0, stream>>>(imn, imx, fmn, fmx);
  k_main<<<NEDGE, 128, 0, stream>>>(Xs, fmn, fmx, anchor, wT, out);
}

// Round 7
// 219.257 us; speedup vs baseline: 1.2094x; 1.0098x over previous
//
#include <hip/hip_runtime.h>
#include <math.h>

#define NEDGE 4000
#define NPE   25
#define DIN   128
#define NPROJ 128
#define NANCH 64
#define NROWS (NEDGE*NPE)   // 100000
#define NBLK  (NROWS/32)    // 3125 gemm blocks

// Reference x-array value at global sorted-row g, replicated bit-exactly:
// x = ((R - Pofs - 1)/(D-1)) * 0.99999f + 1e-5f + seg   (all fp32, no FMA fusion)
__device__ __forceinline__ float xval_of(int g) {
  int ee = g / NPE;
  int jj = g - ee * NPE;
  float t1 = __fdiv_rn((float)jj, 24.0f);
  float t2 = __fmul_rn(t1, 0.99999f);
  float t3 = __fadd_rn(t2, 1e-5f);
  return __fadd_rn(t3, (float)ee);
}

// --- K1: Wt[k][p] = theta[p][k]/||theta[p]|| (transposed for GEMM LDS reads)
//         awT[(2m)*128+p] = anchors[m][p], awT[(2m+1)*128+p] = weight[p][m]
__global__ __launch_bounds__(128) void k_prep(const float* __restrict__ theta,
                                              const float* __restrict__ anchors,
                                              const float* __restrict__ weight,
                                              float* __restrict__ Wt,
                                              float* __restrict__ awT) {
  int p = threadIdx.x;
  float s = 0.f;
  #pragma unroll 8
  for (int k = 0; k < DIN; ++k) { float t = theta[p*DIN + k]; s = fmaf(t, t, s); }
  float nrm = sqrtf(s);
  for (int k = 0; k < DIN; ++k)
    Wt[k*NPROJ + p] = __fdiv_rn(theta[p*DIN + k], nrm);
  #pragma unroll
  for (int m = 0; m < NANCH; ++m) {
    awT[(2*m    )*NPROJ + p] = anchors[m*NPROJ + p];
    awT[(2*m + 1)*NPROJ + p] = weight[p*NANCH + m];
  }
}

// --- K2: Xslices = X @ W^T.  32 rows x 128 cols per block, thread tile 4x4.
// sW staged in FOUR 32-k phases (32KB LDS total).
// Epilogue: per-block per-column min/max from acc registers (exact).
__global__ __launch_bounds__(256) void k_gemm(const float* __restrict__ X,
                                              const float* __restrict__ Wt,
                                              float* __restrict__ Xs,
                                              float* __restrict__ pmin,
                                              float* __restrict__ pmax) {
  __shared__ float sW[32 * NPROJ];   // 16KB, [k][p]
  __shared__ float sX[32 * DIN];     // 16KB, [r][k]
  const int tid = threadIdx.x;
  const int rbase = blockIdx.x * 32;
  {
    const float4* src = (const float4*)(X + (size_t)rbase * DIN);
    float4* dst = (float4*)sX;
    #pragma unroll
    for (int i = 0; i < 4; ++i) dst[tid + 256*i] = src[tid + 256*i];
  }
  const int cg = tid & 31, rg = tid >> 5;
  const int p0 = cg * 4, r0 = rg * 4;
  float acc[4][4] = {};
  for (int ph = 0; ph < 4; ++ph) {
    __syncthreads();   // sX ready / previous phase's sW reads done
    {
      const float4* src = (const float4*)(Wt + ph * 32 * NPROJ);
      float4* dst = (float4*)sW;
      #pragma unroll
      for (int i = 0; i < 4; ++i) dst[tid + 256*i] = src[tid + 256*i];
    }
    __syncthreads();
    #pragma unroll
    for (int k0 = 0; k0 < 32; k0 += 4) {
      float4 w[4];
      #pragma unroll
      for (int i = 0; i < 4; ++i) w[i] = *(const float4*)&sW[(k0+i)*NPROJ + p0];
      #pragma unroll
      for (int i = 0; i < 4; ++i) {
        float4 xv = *(const float4*)&sX[(r0+i)*DIN + ph*32 + k0];
        const float xs[4] = {xv.x, xv.y, xv.z, xv.w};
        #pragma unroll
        for (int kk = 0; kk < 4; ++kk) {
          acc[i][0] = fmaf(xs[kk], w[kk].x, acc[i][0]);
          acc[i][1] = fmaf(xs[kk], w[kk].y, acc[i][1]);
          acc[i][2] = fmaf(xs[kk], w[kk].z, acc[i][2]);
          acc[i][3] = fmaf(xs[kk], w[kk].w, acc[i][3]);
        }
      }
    }
  }
  #pragma unroll
  for (int i = 0; i < 4; ++i) {
    float4 st = make_float4(acc[i][0], acc[i][1], acc[i][2], acc[i][3]);
    *(float4*)&Xs[(size_t)(rbase + r0 + i)*NPROJ + p0] = st;
  }
  // --- fused min/max over this block's 32 rows, per column (reuse sX as scratch)
  __syncthreads();                       // all sX/sW reads done
  float* rmn = sX;                       // [8][128]
  float* rmx = sX + 8*NPROJ;             // [8][128]
  #pragma unroll
  for (int c = 0; c < 4; ++c) {
    float mn = fminf(fminf(acc[0][c], acc[1][c]), fminf(acc[2][c], acc[3][c]));
    float mx = fmaxf(fmaxf(acc[0][c], acc[1][c]), fmaxf(acc[2][c], acc[3][c]));
    rmn[rg*NPROJ + p0 + c] = mn;
    rmx[rg*NPROJ + p0 + c] = mx;
  }
  __syncthreads();
  if (tid < NPROJ) {
    float mn = rmn[tid], mx = rmx[tid];
    #pragma unroll
    for (int g2 = 1; g2 < 8; ++g2) {
      mn = fminf(mn, rmn[g2*NPROJ + tid]);
      mx = fmaxf(mx, rmx[g2*NPROJ + tid]);
    }
    pmin[(size_t)blockIdx.x*NPROJ + tid] = mn;
    pmax[(size_t)blockIdx.x*NPROJ + tid] = mx;
  }
}

// --- K3a: reduce 3125 block-partials -> 25 partials (25 blocks x 125 slots)
__global__ __launch_bounds__(256) void k_red1(const float* __restrict__ pmin,
                                              const float* __restrict__ pmax,
                                              float* __restrict__ imn,
                                              float* __restrict__ imx) {
  __shared__ float smn[NPROJ], smx[NPROJ];
  const int tid = threadIdx.x, p = tid & 127, h = tid >> 7;
  const int b = blockIdx.x;
  float mn = INFINITY, mx = -INFINITY;
  for (int s = 125*b + h; s < 125*(b+1); s += 2) {
    mn = fminf(mn, pmin[(size_t)s*NPROJ + p]);
    mx = fmaxf(mx, pmax[(size_t)s*NPROJ + p]);
  }
  if (h == 1) { smn[p] = mn; smx[p] = mx; }
  __syncthreads();
  if (h == 0) {
    imn[b*NPROJ + p] = fminf(mn, smn[p]);
    imx[b*NPROJ + p] = fmaxf(mx, smx[p]);
  }
}

// --- K3b: reduce 25 partials -> final per-column min/max
__global__ __launch_bounds__(256) void k_red2(const float* __restrict__ imn,
                                              const float* __restrict__ imx,
                                              float* __restrict__ fmn,
                                              float* __restrict__ fmx) {
  __shared__ float smn[NPROJ], smx[NPROJ];
  const int tid = threadIdx.x, p = tid & 127, h = tid >> 7;
  float mn = INFINITY, mx = -INFINITY;
  for (int s = h; s < 25; s += 2) {
    mn = fminf(mn, imn[s*NPROJ + p]);
    mx = fmaxf(mx, imx[s*NPROJ + p]);
  }
  if (h == 1) { smn[p] = mn; smx[p] = mx; }
  __syncthreads();
  if (h == 0) { fmn[p] = fminf(mn, smn[p]); fmx[p] = fmaxf(mx, smx[p]); }
}

// --- K4a: per edge, per column: stable rank-sort of 25 values (u32 keys),
//          sorted rows written back IN-PLACE into Xs (rank r -> row e*25+r).
// Safe: each block reads only its own 25 rows (into registers) before storing.
// Thread p touches only column p (LDS scatter stays in-column -> no barrier).
__global__ __launch_bounds__(128) void k_sort(float* Xs,
                                              const float* __restrict__ fmnA,
                                              const float* __restrict__ fmxA) {
  __shared__ float svals[NPE * NPROJ];
  const int e = blockIdx.x;
  const int p = threadIdx.x;
  const float ef = (float)e;
  const float fmin = fmnA[p];
  const float denom = __fadd_rn(__fsub_rn(fmxA[p], fmin), 1e-12f);

  float v[NPE];
  unsigned ku[NPE];
  #pragma unroll
  for (int j = 0; j < NPE; ++j) {
    float x = Xs[(size_t)(e*NPE + j)*NPROJ + p];
    v[j] = x;
    ku[j] = __float_as_uint(__fadd_rn(__fdiv_rn(__fsub_rn(x, fmin), denom), ef));
  }
  #pragma unroll
  for (int i = 0; i < NPE; ++i) {
    int cnt = 0;
    #pragma unroll
    for (int j = 0; j < NPE; ++j) {
      if (j == i) continue;
      cnt += (j < i) ? (ku[j] <= ku[i]) : (ku[j] < ku[i]);
    }
    svals[cnt*NPROJ + p] = v[i];
  }
  // same-thread LDS writes then reads: lgkmcnt ordering suffices, no barrier
  #pragma unroll
  for (int j = 0; j < NPE; ++j)
    Xs[(size_t)(e*NPE + j)*NPROJ + p] = svals[j*NPROJ + p];
}

// --- K4b: per edge: searchsorted replication + lerp + weighted mean.
// sv rows: [0]=rank23(e-1), [1]=rank24(e-1), [2+r]=rank r of edge e
// -> unified indexing sv[(o+2)*128+p] for o in -2..24, no branches.
__global__ __launch_bounds__(128) void k_epi(const float* __restrict__ Xs,
                                             const float* __restrict__ awT,
                                             float* __restrict__ out) {
  __shared__ float sv[(NPE + 2) * NPROJ];
  __shared__ int   sind[NANCH];
  __shared__ float stt[NANCH];
  const int e = blockIdx.x;
  const int p = threadIdx.x;
  const float ef = (float)e;

  if (e > 0) {
    sv[p]         = Xs[(size_t)((e-1)*NPE + 23)*NPROJ + p];
    sv[NPROJ + p] = Xs[(size_t)((e-1)*NPE + 24)*NPROJ + p];
  }
  #pragma unroll
  for (int j = 0; j < NPE; ++j)
    sv[(2 + j)*NPROJ + p] = Xs[(size_t)(e*NPE + j)*NPROJ + p];

  // searchsorted(x, xnew, side='left'), candidates in [25e-1, 25e+24]
  if (p < NANCH) {
    const int m = p;
    // JAX linspace(0,1,64)[m] = fl(m * fl(1/63))  (no numpy endpoint fixup)
    const float delta = __fdiv_rn(1.0f, 63.0f);
    float g = __fmul_rn((float)m, delta);
    g = __fadd_rn(__fmul_rn(g, 0.99998f), 1e-5f);
    const float xnew = __fadd_rn(ef, g);
    int lo = e*NPE - 1; if (lo < 0) lo = 0;
    const int hi = e*NPE + (NPE - 1);
    int ind = -1;
    for (int j = lo; j <= hi; ++j) {
      float xg = xval_of(j);
      if (ind < 0 && xg >= xnew) ind = j;
    }
    if (ind < 0) ind = hi;
    if (ind < 1) ind = 1;                          // clip(ind, 1, N-1)
    float x0 = xval_of(ind - 1);
    float x1 = xval_of(ind);
    stt[m]  = __fdiv_rn(__fsub_rn(xnew, x0), __fsub_rn(x1, x0));
    sind[m] = ind;
  }
  __syncthreads();

  float acc = 0.f;
  const int base = e * NPE;
  for (int m = 0; m < NANCH; ++m) {
    const int ind = sind[m];
    const float t = stt[m];
    const int o1 = ind - base;       // -1..24  (e=0: >=1)
    const float y1 = sv[(o1 + 2)*NPROJ + p];
    const float y0 = sv[(o1 + 1)*NPROJ + p];
    const float ynew = __fadd_rn(y0, __fmul_rn(__fsub_rn(y1, y0), t));
    const float emb  = __fsub_rn(awT[(2*m)*NPROJ + p], ynew);
    acc = __fadd_rn(acc, __fmul_rn(awT[(2*m + 1)*NPROJ + p], emb));
  }
  out[(size_t)e*NPROJ + p] = __fmul_rn(acc, 0.015625f);   // mean over 64 (exact pow2)
  // second output (edges): harness reads whole d_out as float32 -> store as float
  if (p == 0) out[NEDGE*NPROJ + e] = (float)e;
}

extern "C" void kernel_launch(void* const* d_in, const int* in_sizes, int n_in,
                              void* d_out, int out_size, void* d_ws, size_t ws_size,
                              hipStream_t stream) {
  (void)in_sizes; (void)n_in; (void)out_size; (void)ws_size;
  const float* X      = (const float*)d_in[0];
  const float* theta  = (const float*)d_in[1];
  const float* anchor = (const float*)d_in[2];
  const float* weight = (const float*)d_in[3];
  float* out = (float*)d_out;
  float* ws  = (float*)d_ws;

  float* Xs   = ws;                          // 100000*128
  float* Wt   = Xs   + (size_t)NROWS*NPROJ;  // 128*128
  float* awT  = Wt   + DIN*NPROJ;            // 2*64*128
  float* pmin = awT  + 2*NANCH*NPROJ;        // 3125*128
  float* pmax = pmin + (size_t)NBLK*NPROJ;   // 3125*128
  float* imn  = pmax + (size_t)NBLK*NPROJ;   // 25*128
  float* imx  = imn  + 25*NPROJ;             // 25*128
  float* fmn  = imx  + 25*NPROJ;             // 128
  float* fmx  = fmn  + NPROJ;                // 128

  k_prep<<<1, 128, 0, stream>>>(theta, anchor, weight, Wt, awT);
  k_gemm<<<NBLK, 256, 0, stream>>>(X, Wt, Xs, pmin, pmax);
  k_red1<<<25, 256, 0, stream>>>(pmin, pmax, imn, imx);
  k_red2<<<1, 256, 0, stream>>>(imn, imx, fmn, fmx);
  k_sort<<<NEDGE, 128, 0, stream>>>(Xs, fmn, fmx);
  k_epi <<<NEDGE, 128, 0, stream>>>(Xs, awT, out);
}

// Round 11
// 201.360 us; speedup vs baseline: 1.3169x; 1.0889x over previous
//
#include <hip/hip_runtime.h>
#include <math.h>

#define NEDGE 4000
#define NPE   25
#define DIN   128
#define NPROJ 128
#define NANCH 64
#define NROWS (NEDGE*NPE)   // 100000
#define NBLK  (NROWS/32)    // 3125 gemm blocks

// Reference x-array value at global sorted-row g, replicated bit-exactly:
// x = ((R - Pofs - 1)/(D-1)) * 0.99999f + 1e-5f + seg   (all fp32, no FMA fusion)
__device__ __forceinline__ float xval_of(int g) {
  int ee = g / NPE;
  int jj = g - ee * NPE;
  float t1 = __fdiv_rn((float)jj, 24.0f);
  float t2 = __fmul_rn(t1, 0.99999f);
  float t3 = __fadd_rn(t2, 1e-5f);
  return __fadd_rn(t3, (float)ee);
}

// --- K1 (parallel, EXACT reference arithmetic): blocks 0..127 -> projection p:
// thread 0 runs the reference's sequential fmaf norm chain (identical order to
// the round-3..7 passing k_prep), LDS-broadcast, then 128 threads divide/store.
// Blocks 128..191 -> awT row m: awT[(2m)*128+p]=anchors, awT[(2m+1)*128+p]=weight^T.
__global__ __launch_bounds__(128) void k_prep(const float* __restrict__ theta,
                                              const float* __restrict__ anchors,
                                              const float* __restrict__ weight,
                                              float* __restrict__ Wt,
                                              float* __restrict__ awT) {
  __shared__ float snrm;
  const int t = threadIdx.x;
  if (blockIdx.x < NPROJ) {
    const int p = blockIdx.x;
    if (t == 0) {
      float s = 0.f;
      #pragma unroll 8
      for (int k = 0; k < DIN; ++k) { float x = theta[p*DIN + k]; s = fmaf(x, x, s); }
      snrm = sqrtf(s);
    }
    __syncthreads();
    const float nrm = snrm;
    Wt[t*NPROJ + p] = __fdiv_rn(theta[p*DIN + t], nrm);
  } else {
    const int m = blockIdx.x - NPROJ;      // 0..63
    awT[(2*m    )*NPROJ + t] = anchors[m*NPROJ + t];
    awT[(2*m + 1)*NPROJ + t] = weight[t*NANCH + m];
  }
}

// --- K2: Xslices = X @ W^T.  32 rows x 128 cols per block, thread tile 4x4.
// (verbatim round-7 passing kernel, row-major partials epilogue)
__global__ __launch_bounds__(256) void k_gemm(const float* __restrict__ X,
                                              const float* __restrict__ Wt,
                                              float* __restrict__ Xs,
                                              float* __restrict__ pmin,
                                              float* __restrict__ pmax) {
  __shared__ float sW[32 * NPROJ];   // 16KB, [k][p]
  __shared__ float sX[32 * DIN];     // 16KB, [r][k]
  const int tid = threadIdx.x;
  const int rbase = blockIdx.x * 32;
  {
    const float4* src = (const float4*)(X + (size_t)rbase * DIN);
    float4* dst = (float4*)sX;
    #pragma unroll
    for (int i = 0; i < 4; ++i) dst[tid + 256*i] = src[tid + 256*i];
  }
  const int cg = tid & 31, rg = tid >> 5;
  const int p0 = cg * 4, r0 = rg * 4;
  float acc[4][4] = {};
  for (int ph = 0; ph < 4; ++ph) {
    __syncthreads();   // sX ready / previous phase's sW reads done
    {
      const float4* src = (const float4*)(Wt + ph * 32 * NPROJ);
      float4* dst = (float4*)sW;
      #pragma unroll
      for (int i = 0; i < 4; ++i) dst[tid + 256*i] = src[tid + 256*i];
    }
    __syncthreads();
    #pragma unroll
    for (int k0 = 0; k0 < 32; k0 += 4) {
      float4 w[4];
      #pragma unroll
      for (int i = 0; i < 4; ++i) w[i] = *(const float4*)&sW[(k0+i)*NPROJ + p0];
      #pragma unroll
      for (int i = 0; i < 4; ++i) {
        float4 xv = *(const float4*)&sX[(r0+i)*DIN + ph*32 + k0];
        const float xs[4] = {xv.x, xv.y, xv.z, xv.w};
        #pragma unroll
        for (int kk = 0; kk < 4; ++kk) {
          acc[i][0] = fmaf(xs[kk], w[kk].x, acc[i][0]);
          acc[i][1] = fmaf(xs[kk], w[kk].y, acc[i][1]);
          acc[i][2] = fmaf(xs[kk], w[kk].z, acc[i][2]);
          acc[i][3] = fmaf(xs[kk], w[kk].w, acc[i][3]);
        }
      }
    }
  }
  #pragma unroll
  for (int i = 0; i < 4; ++i) {
    float4 st = make_float4(acc[i][0], acc[i][1], acc[i][2], acc[i][3]);
    *(float4*)&Xs[(size_t)(rbase + r0 + i)*NPROJ + p0] = st;
  }
  // --- fused min/max over this block's 32 rows, per column (reuse sX as scratch)
  __syncthreads();                       // all sX/sW reads done
  float* rmn = sX;                       // [8][128]
  float* rmx = sX + 8*NPROJ;             // [8][128]
  #pragma unroll
  for (int c = 0; c < 4; ++c) {
    float mn = fminf(fminf(acc[0][c], acc[1][c]), fminf(acc[2][c], acc[3][c]));
    float mx = fmaxf(fmaxf(acc[0][c], acc[1][c]), fmaxf(acc[2][c], acc[3][c]));
    rmn[rg*NPROJ + p0 + c] = mn;
    rmx[rg*NPROJ + p0 + c] = mx;
  }
  __syncthreads();
  if (tid < NPROJ) {
    float mn = rmn[tid], mx = rmx[tid];
    #pragma unroll
    for (int g2 = 1; g2 < 8; ++g2) {
      mn = fminf(mn, rmn[g2*NPROJ + tid]);
      mx = fmaxf(mx, rmx[g2*NPROJ + tid]);
    }
    pmin[(size_t)blockIdx.x*NPROJ + tid] = mn;
    pmax[(size_t)blockIdx.x*NPROJ + tid] = mx;
  }
}

// --- K3a: reduce 3125 block-partials -> 25 partials (verbatim round-7, passing)
__global__ __launch_bounds__(256) void k_red1(const float* __restrict__ pmin,
                                              const float* __restrict__ pmax,
                                              float* __restrict__ imn,
                                              float* __restrict__ imx) {
  __shared__ float smn[NPROJ], smx[NPROJ];
  const int tid = threadIdx.x, p = tid & 127, h = tid >> 7;
  const int b = blockIdx.x;
  float mn = INFINITY, mx = -INFINITY;
  for (int s = 125*b + h; s < 125*(b+1); s += 2) {
    mn = fminf(mn, pmin[(size_t)s*NPROJ + p]);
    mx = fmaxf(mx, pmax[(size_t)s*NPROJ + p]);
  }
  if (h == 1) { smn[p] = mn; smx[p] = mx; }
  __syncthreads();
  if (h == 0) {
    imn[b*NPROJ + p] = fminf(mn, smn[p]);
    imx[b*NPROJ + p] = fmaxf(mx, smx[p]);
  }
}

// --- K3b: reduce 25 partials -> final per-column min/max (verbatim round-7)
__global__ __launch_bounds__(256) void k_red2(const float* __restrict__ imn,
                                              const float* __restrict__ imx,
                                              float* __restrict__ fmn,
                                              float* __restrict__ fmx) {
  __shared__ float smn[NPROJ], smx[NPROJ];
  const int tid = threadIdx.x, p = tid & 127, h = tid >> 7;
  float mn = INFINITY, mx = -INFINITY;
  for (int s = h; s < 25; s += 2) {
    mn = fminf(mn, imn[s*NPROJ + p]);
    mx = fmaxf(mx, imx[s*NPROJ + p]);
  }
  if (h == 1) { smn[p] = mn; smx[p] = mx; }
  __syncthreads();
  if (h == 0) { fmn[p] = fminf(mn, smn[p]); fmx[p] = fmaxf(mx, smx[p]); }
}

// --- K4 (fused): per edge: stable rank-sort (u32 keys) of edge e + stable
// top-2 of edge e-1 (prev rows prefetched to regs, latency hidden under sort),
// searchsorted replication, lerp, weighted mean.
// sv rows: [0]=rank23(e-1), [1]=rank24(e-1), [2+r]=rank r of edge e.
// Thread p only touches column p of sv; sind/stt guarded by the barrier.
__global__ __launch_bounds__(128) void k_main(const float* __restrict__ Xs,
                                              const float* __restrict__ fmnA,
                                              const float* __restrict__ fmxA,
                                              const float* __restrict__ awT,
                                              float* __restrict__ out) {
  __shared__ float sv[(NPE + 2) * NPROJ];
  __shared__ int   sind[NANCH];
  __shared__ float stt[NANCH];
  const int e = blockIdx.x;
  const int p = threadIdx.x;
  const float ef = (float)e;
  const float fmin = fmnA[p];
  const float denom = __fadd_rn(__fsub_rn(fmxA[p], fmin), 1e-12f);

  float v[NPE], pv[NPE];
  #pragma unroll
  for (int j = 0; j < NPE; ++j) v[j] = Xs[(size_t)(e*NPE + j)*NPROJ + p];
  if (e > 0) {
    #pragma unroll
    for (int j = 0; j < NPE; ++j) pv[j] = Xs[(size_t)((e-1)*NPE + j)*NPROJ + p];
  }

  unsigned ku[NPE];
  #pragma unroll
  for (int j = 0; j < NPE; ++j)
    ku[j] = __float_as_uint(__fadd_rn(__fdiv_rn(__fsub_rn(v[j], fmin), denom), ef));
  #pragma unroll
  for (int i = 0; i < NPE; ++i) {
    int cnt = 0;
    #pragma unroll
    for (int j = 0; j < NPE; ++j) {
      if (j == i) continue;
      cnt += (j < i) ? (ku[j] <= ku[i]) : (ku[j] < ku[i]);
    }
    sv[(2 + cnt)*NPROJ + p] = v[i];
  }

  if (e > 0) {
    // stable top-2 of prev edge by (key, idx): ties keep LATER index on top
    const float efp = (float)(e - 1);
    unsigned k1 = 0u, k2 = 0u;            // all keys have non-negative bit patterns
    float v1 = 0.f, v2 = 0.f;
    #pragma unroll
    for (int j = 0; j < NPE; ++j) {
      unsigned kk = __float_as_uint(
          __fadd_rn(__fdiv_rn(__fsub_rn(pv[j], fmin), denom), efp));
      if (kk >= k1)      { k2 = k1; v2 = v1; k1 = kk; v1 = pv[j]; }
      else if (kk >= k2) { k2 = kk; v2 = pv[j]; }
    }
    sv[p]         = v2;   // rank 23 of edge e-1
    sv[NPROJ + p] = v1;   // rank 24 of edge e-1
  }

  // searchsorted(x, xnew, side='left'), candidates in [25e-1, 25e+24]
  if (p < NANCH) {
    const int m = p;
    // JAX linspace(0,1,64)[m] = fl(m * fl(1/63))  (no numpy endpoint fixup)
    const float delta = __fdiv_rn(1.0f, 63.0f);
    float g = __fmul_rn((float)m, delta);
    g = __fadd_rn(__fmul_rn(g, 0.99998f), 1e-5f);
    const float xnew = __fadd_rn(ef, g);
    int lo = e*NPE - 1; if (lo < 0) lo = 0;
    const int hi = e*NPE + (NPE - 1);
    int ind = -1;
    for (int j = lo; j <= hi; ++j) {
      float xg = xval_of(j);
      if (ind < 0 && xg >= xnew) ind = j;
    }
    if (ind < 0) ind = hi;
    if (ind < 1) ind = 1;                          // clip(ind, 1, N-1)
    float x0 = xval_of(ind - 1);
    float x1 = xval_of(ind);
    stt[m]  = __fdiv_rn(__fsub_rn(xnew, x0), __fsub_rn(x1, x0));
    sind[m] = ind;
  }
  __syncthreads();

  float acc = 0.f;
  const int base = e * NPE;
  for (int m = 0; m < NANCH; ++m) {
    const int ind = sind[m];
    const float t = stt[m];
    const int o1 = ind - base;       // -1..24 (e=0: >=1, never touches sv[0..1])
    const float y1 = sv[(o1 + 2)*NPROJ + p];
    const float y0 = sv[(o1 + 1)*NPROJ + p];
    const float ynew = __fadd_rn(y0, __fmul_rn(__fsub_rn(y1, y0), t));
    const float emb  = __fsub_rn(awT[(2*m)*NPROJ + p], ynew);
    acc = __fadd_rn(acc, __fmul_rn(awT[(2*m + 1)*NPROJ + p], emb));
  }
  out[(size_t)e*NPROJ + p] = __fmul_rn(acc, 0.015625f);   // mean over 64 (exact pow2)
  // second output (edges): harness reads whole d_out as float32 -> store as float
  if (p == 0) out[NEDGE*NPROJ + e] = (float)e;
}

extern "C" void kernel_launch(void* const* d_in, const int* in_sizes, int n_in,
                              void* d_out, int out_size, void* d_ws, size_t ws_size,
                              hipStream_t stream) {
  (void)in_sizes; (void)n_in; (void)out_size; (void)ws_size;
  const float* X      = (const float*)d_in[0];
  const float* theta  = (const float*)d_in[1];
  const float* anchor = (const float*)d_in[2];
  const float* weight = (const float*)d_in[3];
  float* out = (float*)d_out;
  float* ws  = (float*)d_ws;

  float* Xs   = ws;                          // 100000*128
  float* Wt   = Xs   + (size_t)NROWS*NPROJ;  // 128*128
  float* awT  = Wt   + DIN*NPROJ;            // 2*64*128
  float* pmin = awT  + 2*NANCH*NPROJ;        // 3125*128 (row-major [b][p])
  float* pmax = pmin + (size_t)NBLK*NPROJ;   // 3125*128
  float* imn  = pmax + (size_t)NBLK*NPROJ;   // 25*128
  float* imx  = imn  + 25*NPROJ;             // 25*128
  float* fmn  = imx  + 25*NPROJ;             // 128
  float* fmx  = fmn  + NPROJ;                // 128

  k_prep<<<NPROJ + NANCH, 128, 0, stream>>>(theta, anchor, weight, Wt, awT);
  k_gemm<<<NBLK, 256, 0, stream>>>(X, Wt, Xs, pmin, pmax);
  k_red1<<<25, 256, 0, stream>>>(pmin, pmax, imn, imx);
  k_red2<<<1, 256, 0, stream>>>(imn, imx, fmn, fmx);
  k_main<<<NEDGE, 128, 0, stream>>>(Xs, fmn, fmx, awT, out);
}

// Round 12
// 198.427 us; speedup vs baseline: 1.3364x; 1.0148x over previous
//
#include <hip/hip_runtime.h>
#include <math.h>

#define NEDGE 4000
#define NPE   25
#define DIN   128
#define NPROJ 128
#define NANCH 64
#define NROWS (NEDGE*NPE)        // 100000
#define GBLK  ((NROWS + 63)/64)  // 1563 gemm blocks (last partial: 32 valid rows)

// Reference x-array value at global sorted-row g, replicated bit-exactly:
// x = ((R - Pofs - 1)/(D-1)) * 0.99999f + 1e-5f + seg   (all fp32, no FMA fusion)
__device__ __forceinline__ float xval_of(int g) {
  int ee = g / NPE;
  int jj = g - ee * NPE;
  float t1 = __fdiv_rn((float)jj, 24.0f);
  float t2 = __fmul_rn(t1, 0.99999f);
  float t3 = __fadd_rn(t2, 1e-5f);
  return __fadd_rn(t3, (float)ee);
}

// --- K1 (parallel, EXACT reference arithmetic): blocks 0..127 -> projection p;
// blocks 128..191 -> awT row m. (verbatim round-11, passing)
__global__ __launch_bounds__(128) void k_prep(const float* __restrict__ theta,
                                              const float* __restrict__ anchors,
                                              const float* __restrict__ weight,
                                              float* __restrict__ Wt,
                                              float* __restrict__ awT) {
  __shared__ float snrm;
  const int t = threadIdx.x;
  if (blockIdx.x < NPROJ) {
    const int p = blockIdx.x;
    if (t == 0) {
      float s = 0.f;
      #pragma unroll 8
      for (int k = 0; k < DIN; ++k) { float x = theta[p*DIN + k]; s = fmaf(x, x, s); }
      snrm = sqrtf(s);
    }
    __syncthreads();
    const float nrm = snrm;
    Wt[t*NPROJ + p] = __fdiv_rn(theta[p*DIN + t], nrm);
  } else {
    const int m = blockIdx.x - NPROJ;      // 0..63
    awT[(2*m    )*NPROJ + t] = anchors[m*NPROJ + t];
    awT[(2*m + 1)*NPROJ + t] = weight[t*NANCH + m];
  }
}

// --- K2: Xslices = X @ W^T.  64 rows x 128 cols per block, thread tile 8x4.
// 1.5 B LDS per FMA (vs 2.0 at 4x4) -> lifts the LDS-BW ceiling.
// Per-output FMA chain is ascending k (identical arithmetic to round-11).
// Epilogue: per-block per-column min/max from acc registers (exact).
__global__ __launch_bounds__(256) void k_gemm(const float* __restrict__ X,
                                              const float* __restrict__ Wt,
                                              float* __restrict__ Xs,
                                              float* __restrict__ pmin,
                                              float* __restrict__ pmax) {
  __shared__ float sW[32 * NPROJ];   // 16KB, [k][p]
  __shared__ float sX[64 * DIN];     // 32KB, [r][k]
  const int tid = threadIdx.x;
  const int rbase = blockIdx.x * 64;
  {
    const float4* src = (const float4*)(X + (size_t)rbase * DIN);
    float4* dst = (float4*)sX;
    #pragma unroll
    for (int i = 0; i < 8; ++i) {
      const int idx = tid + 256*i;
      const int row = idx >> 5;                 // 32 float4 per 128-float row
      dst[idx] = (rbase + row < NROWS) ? src[idx] : make_float4(0.f,0.f,0.f,0.f);
    }
  }
  const int cg = tid & 31, rg = tid >> 5;
  const int p0 = cg * 4, r0 = rg * 8;
  float acc[8][4] = {};
  for (int ph = 0; ph < 4; ++ph) {
    __syncthreads();   // sX ready / previous phase's sW reads done
    {
      const float4* src = (const float4*)(Wt + ph * 32 * NPROJ);
      float4* dst = (float4*)sW;
      #pragma unroll
      for (int i = 0; i < 4; ++i) dst[tid + 256*i] = src[tid + 256*i];
    }
    __syncthreads();
    #pragma unroll
    for (int k0 = 0; k0 < 32; k0 += 4) {
      float4 w[4];
      #pragma unroll
      for (int i = 0; i < 4; ++i) w[i] = *(const float4*)&sW[(k0+i)*NPROJ + p0];
      #pragma unroll
      for (int i = 0; i < 8; ++i) {
        float4 xv = *(const float4*)&sX[(r0+i)*DIN + ph*32 + k0];
        const float xs[4] = {xv.x, xv.y, xv.z, xv.w};
        #pragma unroll
        for (int kk = 0; kk < 4; ++kk) {
          acc[i][0] = fmaf(xs[kk], w[kk].x, acc[i][0]);
          acc[i][1] = fmaf(xs[kk], w[kk].y, acc[i][1]);
          acc[i][2] = fmaf(xs[kk], w[kk].z, acc[i][2]);
          acc[i][3] = fmaf(xs[kk], w[kk].w, acc[i][3]);
        }
      }
    }
  }
  #pragma unroll
  for (int i = 0; i < 8; ++i) {
    const int row = rbase + r0 + i;
    if (row < NROWS) {
      float4 st = make_float4(acc[i][0], acc[i][1], acc[i][2], acc[i][3]);
      *(float4*)&Xs[(size_t)row*NPROJ + p0] = st;
    }
  }
  // --- fused min/max over this block's valid rows, per column (reuse sX)
  __syncthreads();                       // all sX/sW reads done
  float* rmn = sX;                       // [8][128]
  float* rmx = sX + 8*NPROJ;             // [8][128]
  const bool valid = (rbase + r0) < NROWS;   // whole 8-row group valid or not
  #pragma unroll
  for (int c = 0; c < 4; ++c) {
    float mn = INFINITY, mx = -INFINITY;
    if (valid) {
      #pragma unroll
      for (int i = 0; i < 8; ++i) {
        mn = fminf(mn, acc[i][c]);
        mx = fmaxf(mx, acc[i][c]);
      }
    }
    rmn[rg*NPROJ + p0 + c] = mn;
    rmx[rg*NPROJ + p0 + c] = mx;
  }
  __syncthreads();
  if (tid < NPROJ) {
    float mn = rmn[tid], mx = rmx[tid];
    #pragma unroll
    for (int g2 = 1; g2 < 8; ++g2) {
      mn = fminf(mn, rmn[g2*NPROJ + tid]);
      mx = fmaxf(mx, rmx[g2*NPROJ + tid]);
    }
    pmin[(size_t)blockIdx.x*NPROJ + tid] = mn;
    pmax[(size_t)blockIdx.x*NPROJ + tid] = mx;
  }
}

// --- K3a: reduce 1563 block-partials -> 25 partials (25 blocks x 63 slots)
__global__ __launch_bounds__(256) void k_red1(const float* __restrict__ pmin,
                                              const float* __restrict__ pmax,
                                              float* __restrict__ imn,
                                              float* __restrict__ imx) {
  __shared__ float smn[NPROJ], smx[NPROJ];
  const int tid = threadIdx.x, p = tid & 127, h = tid >> 7;
  const int b = blockIdx.x;
  const int s1 = min(63*(b+1), GBLK);
  float mn = INFINITY, mx = -INFINITY;
  for (int s = 63*b + h; s < s1; s += 2) {
    mn = fminf(mn, pmin[(size_t)s*NPROJ + p]);
    mx = fmaxf(mx, pmax[(size_t)s*NPROJ + p]);
  }
  if (h == 1) { smn[p] = mn; smx[p] = mx; }
  __syncthreads();
  if (h == 0) {
    imn[b*NPROJ + p] = fminf(mn, smn[p]);
    imx[b*NPROJ + p] = fmaxf(mx, smx[p]);
  }
}

// --- K3b: reduce 25 partials -> final per-column min/max (verbatim round-11)
__global__ __launch_bounds__(256) void k_red2(const float* __restrict__ imn,
                                              const float* __restrict__ imx,
                                              float* __restrict__ fmn,
                                              float* __restrict__ fmx) {
  __shared__ float smn[NPROJ], smx[NPROJ];
  const int tid = threadIdx.x, p = tid & 127, h = tid >> 7;
  float mn = INFINITY, mx = -INFINITY;
  for (int s = h; s < 25; s += 2) {
    mn = fminf(mn, imn[s*NPROJ + p]);
    mx = fmaxf(mx, imx[s*NPROJ + p]);
  }
  if (h == 1) { smn[p] = mn; smx[p] = mx; }
  __syncthreads();
  if (h == 0) { fmn[p] = fminf(mn, smn[p]); fmx[p] = fmaxf(mx, smx[p]); }
}

// --- K4 (fused): per edge: stable rank-sort (u32 keys) of edge e + stable
// top-2 of edge e-1, searchsorted replication, lerp, weighted mean.
// (verbatim round-11, passing)
__global__ __launch_bounds__(128) void k_main(const float* __restrict__ Xs,
                                              const float* __restrict__ fmnA,
                                              const float* __restrict__ fmxA,
                                              const float* __restrict__ awT,
                                              float* __restrict__ out) {
  __shared__ float sv[(NPE + 2) * NPROJ];
  __shared__ int   sind[NANCH];
  __shared__ float stt[NANCH];
  const int e = blockIdx.x;
  const int p = threadIdx.x;
  const float ef = (float)e;
  const float fmin = fmnA[p];
  const float denom = __fadd_rn(__fsub_rn(fmxA[p], fmin), 1e-12f);

  float v[NPE], pv[NPE];
  #pragma unroll
  for (int j = 0; j < NPE; ++j) v[j] = Xs[(size_t)(e*NPE + j)*NPROJ + p];
  if (e > 0) {
    #pragma unroll
    for (int j = 0; j < NPE; ++j) pv[j] = Xs[(size_t)((e-1)*NPE + j)*NPROJ + p];
  }

  unsigned ku[NPE];
  #pragma unroll
  for (int j = 0; j < NPE; ++j)
    ku[j] = __float_as_uint(__fadd_rn(__fdiv_rn(__fsub_rn(v[j], fmin), denom), ef));
  #pragma unroll
  for (int i = 0; i < NPE; ++i) {
    int cnt = 0;
    #pragma unroll
    for (int j = 0; j < NPE; ++j) {
      if (j == i) continue;
      cnt += (j < i) ? (ku[j] <= ku[i]) : (ku[j] < ku[i]);
    }
    sv[(2 + cnt)*NPROJ + p] = v[i];
  }

  if (e > 0) {
    // stable top-2 of prev edge by (key, idx): ties keep LATER index on top
    const float efp = (float)(e - 1);
    unsigned k1 = 0u, k2 = 0u;            // all keys have non-negative bit patterns
    float v1 = 0.f, v2 = 0.f;
    #pragma unroll
    for (int j = 0; j < NPE; ++j) {
      unsigned kk = __float_as_uint(
          __fadd_rn(__fdiv_rn(__fsub_rn(pv[j], fmin), denom), efp));
      if (kk >= k1)      { k2 = k1; v2 = v1; k1 = kk; v1 = pv[j]; }
      else if (kk >= k2) { k2 = kk; v2 = pv[j]; }
    }
    sv[p]         = v2;   // rank 23 of edge e-1
    sv[NPROJ + p] = v1;   // rank 24 of edge e-1
  }

  // searchsorted(x, xnew, side='left'), candidates in [25e-1, 25e+24]
  if (p < NANCH) {
    const int m = p;
    // JAX linspace(0,1,64)[m] = fl(m * fl(1/63))  (no numpy endpoint fixup)
    const float delta = __fdiv_rn(1.0f, 63.0f);
    float g = __fmul_rn((float)m, delta);
    g = __fadd_rn(__fmul_rn(g, 0.99998f), 1e-5f);
    const float xnew = __fadd_rn(ef, g);
    int lo = e*NPE - 1; if (lo < 0) lo = 0;
    const int hi = e*NPE + (NPE - 1);
    int ind = -1;
    for (int j = lo; j <= hi; ++j) {
      float xg = xval_of(j);
      if (ind < 0 && xg >= xnew) ind = j;
    }
    if (ind < 0) ind = hi;
    if (ind < 1) ind = 1;                          // clip(ind, 1, N-1)
    float x0 = xval_of(ind - 1);
    float x1 = xval_of(ind);
    stt[m]  = __fdiv_rn(__fsub_rn(xnew, x0), __fsub_rn(x1, x0));
    sind[m] = ind;
  }
  __syncthreads();

  float acc = 0.f;
  const int base = e * NPE;
  for (int m = 0; m < NANCH; ++m) {
    const int ind = sind[m];
    const float t = stt[m];
    const int o1 = ind - base;       // -1..24 (e=0: >=1, never touches sv[0..1])
    const float y1 = sv[(o1 + 2)*NPROJ + p];
    const float y0 = sv[(o1 + 1)*NPROJ + p];
    const float ynew = __fadd_rn(y0, __fmul_rn(__fsub_rn(y1, y0), t));
    const float emb  = __fsub_rn(awT[(2*m)*NPROJ + p], ynew);
    acc = __fadd_rn(acc, __fmul_rn(awT[(2*m + 1)*NPROJ + p], emb));
  }
  out[(size_t)e*NPROJ + p] = __fmul_rn(acc, 0.015625f);   // mean over 64 (exact pow2)
  // second output (edges): harness reads whole d_out as float32 -> store as float
  if (p == 0) out[NEDGE*NPROJ + e] = (float)e;
}

extern "C" void kernel_launch(void* const* d_in, const int* in_sizes, int n_in,
                              void* d_out, int out_size, void* d_ws, size_t ws_size,
                              hipStream_t stream) {
  (void)in_sizes; (void)n_in; (void)out_size; (void)ws_size;
  const float* X      = (const float*)d_in[0];
  const float* theta  = (const float*)d_in[1];
  const float* anchor = (const float*)d_in[2];
  const float* weight = (const float*)d_in[3];
  float* out = (float*)d_out;
  float* ws  = (float*)d_ws;

  float* Xs   = ws;                          // 100000*128
  float* Wt   = Xs   + (size_t)NROWS*NPROJ;  // 128*128
  float* awT  = Wt   + DIN*NPROJ;            // 2*64*128
  float* pmin = awT  + 2*NANCH*NPROJ;        // 1563*128 (row-major [b][p])
  float* pmax = pmin + (size_t)GBLK*NPROJ;   // 1563*128
  float* imn  = pmax + (size_t)GBLK*NPROJ;   // 25*128
  float* imx  = imn  + 25*NPROJ;             // 25*128
  float* fmn  = imx  + 25*NPROJ;             // 128
  float* fmx  = fmn  + NPROJ;                // 128

  k_prep<<<NPROJ + NANCH, 128, 0, stream>>>(theta, anchor, weight, Wt, awT);
  k_gemm<<<GBLK, 256, 0, stream>>>(X, Wt, Xs, pmin, pmax);
  k_red1<<<25, 256, 0, stream>>>(pmin, pmax, imn, imx);
  k_red2<<<1, 256, 0, stream>>>(imn, imx, fmn, fmx);
  k_main<<<NEDGE, 128, 0, stream>>>(Xs, fmn, fmx, awT, out);
}